// Round 1
// baseline (417.650 us; speedup 1.0000x reference)
//
#include <hip/hip_runtime.h>

// Problem constants
#define B_  64
#define N1_ 8
#define KK  128
#define EE  256
#define HH  512
#define BN  (B_ * N1_)   // 512

// ---------------------------------------------------------------------------
// Kernel 1: q_proj[bn][h] = dot(queries[bn,:], wq_w[h,:]) + wq_b[h]
// grid = BN, block = 256 (each thread computes h = t and t+256)
// ---------------------------------------------------------------------------
__global__ __launch_bounds__(256) void k_qproj(
    const float* __restrict__ queries,
    const float* __restrict__ wq_w,
    const float* __restrict__ wq_b,
    float* __restrict__ qp) {
  int bn = blockIdx.x;
  int t = threadIdx.x;
  __shared__ float q[EE];
  q[t] = queries[bn * EE + t];
  __syncthreads();
  const float4* q4 = (const float4*)q;
  #pragma unroll
  for (int hh = 0; hh < 2; ++hh) {
    int h = t + hh * 256;
    const float4* w4 = (const float4*)(wq_w + (size_t)h * EE);
    float acc = 0.f;
    #pragma unroll 8
    for (int e4 = 0; e4 < EE / 4; ++e4) {
      float4 w = w4[e4];
      float4 qv = q4[e4];
      acc += w.x * qv.x + w.y * qv.y + w.z * qv.z + w.w * qv.w;
    }
    qp[bn * HH + h] = acc + wq_b[h];
  }
}

// ---------------------------------------------------------------------------
// Kernel 2: scores[bn][k] = sum_h wv_w[h]*tanh(qp[bn][h] + wk_b[h]
//                                 + dot(keys[bn,k,:], wk_w[h,:])) + wv_b
// grid = BN*4 (k-tiles of 32), block = 256 (thread owns h = t and t+256)
// keys tile (32 x 256 f32 = 32 KB) staged in LDS; LDS reads are wave-uniform
// broadcasts (no bank conflicts); wk_w streamed per-thread from L2.
// ---------------------------------------------------------------------------
__global__ __launch_bounds__(256) void k_scores(
    const float* __restrict__ keys,
    const float* __restrict__ wk_w,
    const float* __restrict__ wk_b,
    const float* __restrict__ wv_w,
    const float* __restrict__ wv_b,
    const float* __restrict__ qp,
    float* __restrict__ scores) {
  int bx = blockIdx.x;
  int bn = bx >> 2;
  int kt = bx & 3;            // which 32-key tile
  int t  = threadIdx.x;

  __shared__ float4 lk[32 * 64];   // 32 keys x 256 floats (as float4)
  const float4* kb4 = (const float4*)(keys + (size_t)bn * KK * EE + (size_t)kt * 32 * EE);
  #pragma unroll
  for (int i = 0; i < 8; ++i) lk[i * 256 + t] = kb4[i * 256 + t];
  __syncthreads();

  const int h0 = t, h1 = t + 256;
  float a0[32], a1[32];
  #pragma unroll
  for (int kk = 0; kk < 32; ++kk) { a0[kk] = 0.f; a1[kk] = 0.f; }

  const float4* w04 = (const float4*)(wk_w + (size_t)h0 * EE);
  const float4* w14 = (const float4*)(wk_w + (size_t)h1 * EE);

  for (int e4 = 0; e4 < 64; ++e4) {
    float4 w0 = w04[e4];
    float4 w1 = w14[e4];
    #pragma unroll
    for (int kk = 0; kk < 32; ++kk) {
      float4 kv = lk[kk * 64 + e4];   // uniform address -> broadcast
      a0[kk] += w0.x * kv.x + w0.y * kv.y + w0.z * kv.z + w0.w * kv.w;
      a1[kk] += w1.x * kv.x + w1.y * kv.y + w1.z * kv.z + w1.w * kv.w;
    }
  }

  float b0 = wk_b[h0] + qp[bn * HH + h0];
  float b1 = wk_b[h1] + qp[bn * HH + h1];
  float v0 = wv_w[h0], v1 = wv_w[h1];

  float c[32];
  #pragma unroll
  for (int kk = 0; kk < 32; ++kk)
    c[kk] = v0 * tanhf(a0[kk] + b0) + v1 * tanhf(a1[kk] + b1);

  // reduce c[kk] across the 256 threads: wave butterfly, then LDS partials
  #pragma unroll
  for (int kk = 0; kk < 32; ++kk) {
    #pragma unroll
    for (int off = 32; off >= 1; off >>= 1)
      c[kk] += __shfl_xor(c[kk], off, 64);
  }
  __shared__ float part[4][32];
  int lane = t & 63, wid = t >> 6;
  if (lane == 0) {
    #pragma unroll
    for (int kk = 0; kk < 32; ++kk) part[wid][kk] = c[kk];
  }
  __syncthreads();
  if (t < 32) {
    scores[bn * KK + kt * 32 + t] =
        part[0][t] + part[1][t] + part[2][t] + part[3][t] + wv_b[0];
  }
}

// ---------------------------------------------------------------------------
// Kernel 3: masked softmax over K, write attn_weight, then
// attn_out[bn][e] = sum_k w[k] * keys[bn,k,e]
// grid = BN, block = 256 (thread = e)
// ---------------------------------------------------------------------------
__global__ __launch_bounds__(256) void k_softmax_out(
    const float* __restrict__ keys,
    const int* __restrict__ masks,
    const float* __restrict__ scores,
    float* __restrict__ out) {
  int bn = blockIdx.x;
  int t  = threadIdx.x;
  __shared__ float sw[KK];
  __shared__ float red;

  if (t < KK) {
    float s = scores[bn * KK + t] + (float)masks[bn * KK + t] * (-1e9f);
    sw[t] = s;
  }
  __syncthreads();
  if (t == 0) {
    float m = sw[0];
    for (int k = 1; k < KK; ++k) m = fmaxf(m, sw[k]);
    red = m;
  }
  __syncthreads();
  float m = red;
  if (t < KK) sw[t] = expf(sw[t] - m);
  __syncthreads();
  if (t == 0) {
    float s = 0.f;
    for (int k = 0; k < KK; ++k) s += sw[k];
    red = s;
  }
  __syncthreads();
  float inv = 1.f / red;
  if (t < KK) {
    float w = sw[t] * inv;
    sw[t] = w;
    out[BN * EE + bn * KK + t] = w;   // attn_weight output (offset after attn_out)
  }
  __syncthreads();

  const float* kb = keys + (size_t)bn * KK * EE;
  float acc = 0.f;
  #pragma unroll 8
  for (int k = 0; k < KK; ++k)
    acc += sw[k] * kb[k * EE + t];    // coalesced over e = t
  out[bn * EE + t] = acc;
}

// ---------------------------------------------------------------------------
extern "C" void kernel_launch(void* const* d_in, const int* in_sizes, int n_in,
                              void* d_out, int out_size, void* d_ws, size_t ws_size,
                              hipStream_t stream) {
  const float* queries = (const float*)d_in[0];
  const float* keys    = (const float*)d_in[1];
  const int*   masks   = (const int*)d_in[2];
  // d_in[3] = num_neg (unused by the reference computation)
  const float* wk_w = (const float*)d_in[4];
  const float* wk_b = (const float*)d_in[5];
  const float* wq_w = (const float*)d_in[6];
  const float* wq_b = (const float*)d_in[7];
  const float* wv_w = (const float*)d_in[8];
  const float* wv_b = (const float*)d_in[9];

  float* out    = (float*)d_out;
  float* qp     = (float*)d_ws;          // BN*HH f32 = 1 MB
  float* scores = qp + BN * HH;          // BN*KK f32 = 256 KB

  k_qproj<<<BN, 256, 0, stream>>>(queries, wq_w, wq_b, qp);
  k_scores<<<BN * 4, 256, 0, stream>>>(keys, wk_w, wk_b, wv_w, wv_b, qp, scores);
  k_softmax_out<<<BN, 256, 0, stream>>>(keys, masks, scores, out);
}

// Round 3
// 175.667 us; speedup vs baseline: 2.3775x; 2.3775x over previous
//
#include <hip/hip_runtime.h>

// Problem constants
#define B_  64
#define N1_ 8
#define KK  128
#define EE  256
#define HH  512
#define BN  (B_ * N1_)   // 512
#define NROWS (BN * KK)  // 65536 key-rows

typedef __attribute__((ext_vector_type(8))) short short8;   // bf16x8 MFMA frag
typedef __attribute__((ext_vector_type(4))) float f32x4;    // MFMA acc

__device__ __forceinline__ unsigned short f2bf(float f) {
  union { float f; unsigned int u; } v; v.f = f;
  unsigned int r = (v.u + 0x7fffu + ((v.u >> 16) & 1u)) >> 16;  // RNE
  return (unsigned short)r;
}

__device__ __forceinline__ float tanhf_fast(float x) {
  // tanh(x) = 1 - 2/(exp(2x)+1);  exp(2x) = exp2(2*log2e*x)
  float e2 = __builtin_amdgcn_exp2f(2.8853900817779268f * x);  // 2/ln(2) * x
  return 1.0f - 2.0f * __builtin_amdgcn_rcpf(e2 + 1.0f);
}

// ---------------------------------------------------------------------------
// Kernel 0: wk_w f32 -> bf16 copy (row-major, 512x256)
// ---------------------------------------------------------------------------
__global__ __launch_bounds__(256) void k_wk_bf16(
    const float* __restrict__ wk_w, unsigned short* __restrict__ wk_bf) {
  int i = blockIdx.x * 256 + threadIdx.x;   // grid 512 blocks -> 131072
  wk_bf[i] = f2bf(wk_w[i]);
}

// ---------------------------------------------------------------------------
// Kernel 1: q_proj[bn][h] = dot(queries[bn,:], wq_w[h,:]) + wq_b[h]  (f32)
// ---------------------------------------------------------------------------
__global__ __launch_bounds__(256) void k_qproj(
    const float* __restrict__ queries,
    const float* __restrict__ wq_w,
    const float* __restrict__ wq_b,
    float* __restrict__ qp) {
  int bn = blockIdx.x;
  int t = threadIdx.x;
  __shared__ float q[EE];
  q[t] = queries[bn * EE + t];
  __syncthreads();
  const float4* q4 = (const float4*)q;
  #pragma unroll
  for (int hh = 0; hh < 2; ++hh) {
    int h = t + hh * 256;
    const float4* w4 = (const float4*)(wq_w + (size_t)h * EE);
    float acc = 0.f;
    #pragma unroll 8
    for (int e4 = 0; e4 < EE / 4; ++e4) {
      float4 w = w4[e4];
      float4 qv = q4[e4];
      acc += w.x * qv.x + w.y * qv.y + w.z * qv.z + w.w * qv.w;
    }
    qp[bn * HH + h] = acc + wq_b[h];
  }
}

// ---------------------------------------------------------------------------
// Kernel 2 (MFMA): scores[row] = sum_h wv_w[h]*tanh(qp[bn][h]+wk_b[h]
//                               + dot(keys[row,:], wk_w[h,:])) + wv_b
// Block = 256 thr (4 waves), 64 rows/block (16 rows/wave). No LDS.
// D[key][h] tiles via mfma_f32_16x16x32_bf16:
//   A slot: row = lane&15 (key), 8 consecutive e at (lane>>4)*8 + 32*s
//   B slot: col = lane&15 (h),   8 consecutive e (same k-slot mapping)
//   C/D:    col = lane&15 (h),   row = (lane>>4)*4 + reg (key)   [m89]
// Any consistent slot->e permutation of A and B leaves the dot invariant.
// ---------------------------------------------------------------------------
__global__ __launch_bounds__(256) void k_scores_mfma(
    const float* __restrict__ keys,
    const unsigned short* __restrict__ wk_bf,
    const float* __restrict__ wk_b,
    const float* __restrict__ wv_w,
    const float* __restrict__ wv_b,
    const float* __restrict__ qp,
    float* __restrict__ scores) {
  const int t = threadIdx.x;
  const int w = t >> 6;          // wave 0..3
  const int l = t & 63;          // lane
  const int lg = l >> 4;         // lane group 0..3
  const int ll = l & 15;

  const int row0 = blockIdx.x * 64 + w * 16;   // this wave's 16 key-rows
  const int bn = blockIdx.x >> 1;              // 64 rows = half of one bn's K=128

  // --- load this wave's 16x256 keys tile as 8 bf16 fragments (in regs) ---
  short8 afrag[8];
  {
    const float* kp = keys + (size_t)(row0 + ll) * EE + lg * 8;
    #pragma unroll
    for (int s = 0; s < 8; ++s) {
      float4 x = *(const float4*)(kp + s * 32);
      float4 y = *(const float4*)(kp + s * 32 + 4);
      short8 f;
      f[0] = (short)f2bf(x.x); f[1] = (short)f2bf(x.y);
      f[2] = (short)f2bf(x.z); f[3] = (short)f2bf(x.w);
      f[4] = (short)f2bf(y.x); f[5] = (short)f2bf(y.y);
      f[6] = (short)f2bf(y.z); f[7] = (short)f2bf(y.w);
      afrag[s] = f;
    }
  }

  float partial[4] = {0.f, 0.f, 0.f, 0.f};

  for (int ht = 0; ht < HH / 16; ++ht) {       // 32 h-tiles
    const int h = ht * 16 + ll;
    // B fragments: wk_bf[h][e], 8 consecutive e per slot
    const unsigned short* bp = wk_bf + (size_t)h * EE + lg * 8;
    f32x4 acc = {0.f, 0.f, 0.f, 0.f};
    #pragma unroll
    for (int s = 0; s < 8; ++s) {
      short8 bfrag = *(const short8*)(bp + s * 32);
      acc = __builtin_amdgcn_mfma_f32_16x16x32_bf16(afrag[s], bfrag, acc, 0, 0, 0);
    }
    const float qb = qp[bn * HH + h] + wk_b[h];
    const float wv = wv_w[h];
    #pragma unroll
    for (int r = 0; r < 4; ++r)
      partial[r] += wv * tanhf_fast(acc[r] + qb);
  }

  // reduce over h: sum across the 16 lanes of each lane-group
  #pragma unroll
  for (int r = 0; r < 4; ++r) {
    #pragma unroll
    for (int off = 1; off <= 8; off <<= 1)
      partial[r] += __shfl_xor(partial[r], off, 64);
  }

  if (ll == 0) {
    const float vb = wv_b[0];
    #pragma unroll
    for (int r = 0; r < 4; ++r)
      scores[row0 + lg * 4 + r] = partial[r] + vb;
  }
}

// ---------------------------------------------------------------------------
// Kernel 3: masked softmax over K, write attn_weight, then
// attn_out[bn][e] = sum_k w[k] * keys[bn,k,e]
// ---------------------------------------------------------------------------
__global__ __launch_bounds__(256) void k_softmax_out(
    const float* __restrict__ keys,
    const int* __restrict__ masks,
    const float* __restrict__ scores,
    float* __restrict__ out) {
  int bn = blockIdx.x;
  int t  = threadIdx.x;
  __shared__ float sw[KK];
  __shared__ float red;

  if (t < KK) {
    float s = scores[bn * KK + t] + (float)masks[bn * KK + t] * (-1e9f);
    sw[t] = s;
  }
  __syncthreads();
  if (t == 0) {
    float m = sw[0];
    for (int k = 1; k < KK; ++k) m = fmaxf(m, sw[k]);
    red = m;
  }
  __syncthreads();
  float m = red;
  if (t < KK) sw[t] = expf(sw[t] - m);
  __syncthreads();
  if (t == 0) {
    float s = 0.f;
    for (int k = 0; k < KK; ++k) s += sw[k];
    red = s;
  }
  __syncthreads();
  float inv = 1.f / red;
  if (t < KK) {
    float wgt = sw[t] * inv;
    sw[t] = wgt;
    out[BN * EE + bn * KK + t] = wgt;   // attn_weight (after attn_out)
  }
  __syncthreads();

  const float* kb = keys + (size_t)bn * KK * EE;
  float acc = 0.f;
  #pragma unroll 8
  for (int k = 0; k < KK; ++k)
    acc += sw[k] * kb[k * EE + t];      // coalesced over e = t
  out[bn * EE + t] = acc;
}

// ---------------------------------------------------------------------------
extern "C" void kernel_launch(void* const* d_in, const int* in_sizes, int n_in,
                              void* d_out, int out_size, void* d_ws, size_t ws_size,
                              hipStream_t stream) {
  const float* queries = (const float*)d_in[0];
  const float* keys    = (const float*)d_in[1];
  const int*   masks   = (const int*)d_in[2];
  // d_in[3] = num_neg (unused)
  const float* wk_w = (const float*)d_in[4];
  const float* wk_b = (const float*)d_in[5];
  const float* wq_w = (const float*)d_in[6];
  const float* wq_b = (const float*)d_in[7];
  const float* wv_w = (const float*)d_in[8];
  const float* wv_b = (const float*)d_in[9];

  float* out    = (float*)d_out;
  float* qp     = (float*)d_ws;                       // 512*512 f32   = 1 MB
  float* scores = qp + BN * HH;                       // 65536 f32     = 256 KB
  unsigned short* wk_bf = (unsigned short*)(scores + NROWS);  // 131072 bf16 = 256 KB

  k_wk_bf16<<<512, 256, 0, stream>>>(wk_w, wk_bf);
  k_qproj<<<BN, 256, 0, stream>>>(queries, wq_w, wq_b, qp);
  k_scores_mfma<<<NROWS / 64, 256, 0, stream>>>(keys, wk_bf, wk_b, wv_w, wv_b, qp, scores);
  k_softmax_out<<<BN, 256, 0, stream>>>(keys, masks, scores, out);
}

// Round 4
// 81.703 us; speedup vs baseline: 5.1118x; 2.1501x over previous
//
#include <hip/hip_runtime.h>

// Problem constants
#define B_  64
#define N1_ 8
#define KK  128
#define EE  256
#define HH  512
#define BN  (B_ * N1_)   // 512
#define NROWS (BN * KK)  // 65536 key-rows

typedef __attribute__((ext_vector_type(8))) short short8;   // bf16x8 MFMA frag
typedef __attribute__((ext_vector_type(4))) float f32x4;    // MFMA acc

__device__ __forceinline__ unsigned short f2bf(float f) {
  union { float f; unsigned int u; } v; v.f = f;
  unsigned int r = (v.u + 0x7fffu + ((v.u >> 16) & 1u)) >> 16;  // RNE
  return (unsigned short)r;
}

__device__ __forceinline__ float tanhf_fast(float x) {
  // tanh(x) = 1 - 2/(exp(2x)+1);  exp(2x) = exp2(2*log2e*x)
  float e2 = __builtin_amdgcn_exp2f(2.8853900817779268f * x);
  return 1.0f - 2.0f * __builtin_amdgcn_rcpf(e2 + 1.0f);
}

// ---------------------------------------------------------------------------
// Kernel 0: wk_w f32 -> bf16 (512x256 row-major)
// ---------------------------------------------------------------------------
__global__ __launch_bounds__(256) void k_wk_bf16(
    const float* __restrict__ wk_w, unsigned short* __restrict__ wk_bf) {
  int i = blockIdx.x * 256 + threadIdx.x;
  wk_bf[i] = f2bf(wk_w[i]);
}

// ---------------------------------------------------------------------------
// Kernel 1: q_proj[bn][h] = dot(queries[bn,:], wq_w[h,:]) + wq_b[h]  (f32)
// ---------------------------------------------------------------------------
__global__ __launch_bounds__(256) void k_qproj(
    const float* __restrict__ queries,
    const float* __restrict__ wq_w,
    const float* __restrict__ wq_b,
    float* __restrict__ qp) {
  int bn = blockIdx.x;
  int t = threadIdx.x;
  __shared__ float q[EE];
  q[t] = queries[bn * EE + t];
  __syncthreads();
  const float4* q4 = (const float4*)q;
  #pragma unroll
  for (int hh = 0; hh < 2; ++hh) {
    int h = t + hh * 256;
    const float4* w4 = (const float4*)(wq_w + (size_t)h * EE);
    float acc = 0.f;
    #pragma unroll 8
    for (int e4 = 0; e4 < EE / 4; ++e4) {
      float4 w = w4[e4];
      float4 qv = q4[e4];
      acc += w.x * qv.x + w.y * qv.y + w.z * qv.z + w.w * qv.w;
    }
    qp[bn * HH + h] = acc + wq_b[h];
  }
}

// ---------------------------------------------------------------------------
// Kernel 2 (fused): one block = one bn (128 key-rows). 4 waves x 32 rows.
//   scores -> masked softmax over K -> attn_weight + attn_out.
// wk tiles (16 h x 256 e bf16 = 8 KB) double-buffered in LDS, XOR-swizzled,
// one barrier per tile; each wave runs 2 independent MFMA chains.
// MFMA 16x16x32 C/D: col(h)=lane&15, row(key)=(lane>>4)*4+reg   [m89]
// ---------------------------------------------------------------------------
__global__ __launch_bounds__(256) void k_fused(
    const float* __restrict__ keys,
    const unsigned short* __restrict__ wk_bf,
    const float* __restrict__ wk_b,
    const float* __restrict__ wv_w,
    const float* __restrict__ qp,
    const int* __restrict__ masks,
    float* __restrict__ out) {
  const int t  = threadIdx.x;
  const int w  = t >> 6;      // wave 0..3
  const int l  = t & 63;
  const int lg = l >> 4;      // lane group 0..3
  const int ll = l & 15;
  const int bn = blockIdx.x;

  __shared__ char bsm[2][16 * 512];   // 2 x 8 KB wk tiles (bf16, swizzled)
  __shared__ float sc[KK];
  __shared__ float red[2];

  // --- per-thread staging chunks: tile = 512 x 16B chunks ---
  const char* wkb = (const char*)wk_bf;            // 512 rows x 512 B
  const int c0 = t, c1 = t + 256;
  const int hl0 = c0 >> 5, of0 = (c0 & 31) * 16;
  const int hl1 = c1 >> 5, of1 = (c1 & 31) * 16;
  const int d0 = hl0 * 512 + (of0 ^ ((hl0 & 7) << 4));
  const int d1 = hl1 * 512 + (of1 ^ ((hl1 & 7) << 4));

  // --- prologue: stage tile 0 ---
  int4 s0 = *(const int4*)(wkb + (size_t)hl0 * 512 + of0);
  int4 s1 = *(const int4*)(wkb + (size_t)hl1 * 512 + of1);
  *(int4*)(bsm[0] + d0) = s0;
  *(int4*)(bsm[0] + d1) = s1;

  // --- load this wave's 2 x (16 rows x 256 e) keys tiles as bf16 frags ---
  short8 af0[8], af1[8];
  {
    const int row0 = bn * KK + w * 32;
    const float* kp0 = keys + (size_t)(row0 + ll) * EE + lg * 8;
    const float* kp1 = keys + (size_t)(row0 + 16 + ll) * EE + lg * 8;
    #pragma unroll
    for (int s = 0; s < 8; ++s) {
      float4 x = *(const float4*)(kp0 + s * 32);
      float4 y = *(const float4*)(kp0 + s * 32 + 4);
      short8 f;
      f[0] = (short)f2bf(x.x); f[1] = (short)f2bf(x.y);
      f[2] = (short)f2bf(x.z); f[3] = (short)f2bf(x.w);
      f[4] = (short)f2bf(y.x); f[5] = (short)f2bf(y.y);
      f[6] = (short)f2bf(y.z); f[7] = (short)f2bf(y.w);
      af0[s] = f;
      x = *(const float4*)(kp1 + s * 32);
      y = *(const float4*)(kp1 + s * 32 + 4);
      f[0] = (short)f2bf(x.x); f[1] = (short)f2bf(x.y);
      f[2] = (short)f2bf(x.z); f[3] = (short)f2bf(x.w);
      f[4] = (short)f2bf(y.x); f[5] = (short)f2bf(y.y);
      f[6] = (short)f2bf(y.z); f[7] = (short)f2bf(y.w);
      af1[s] = f;
    }
  }
  __syncthreads();

  float p0[4] = {0.f, 0.f, 0.f, 0.f};
  float p1[4] = {0.f, 0.f, 0.f, 0.f};

  for (int ht = 0; ht < HH / 16; ++ht) {     // 32 wk tiles
    // issue next tile's global loads early (latency hides under MFMA)
    int4 n0, n1;
    if (ht < 31) {
      const char* src = wkb + (size_t)(ht + 1) * 16 * 512;
      n0 = *(const int4*)(src + (size_t)hl0 * 512 + of0);
      n1 = *(const int4*)(src + (size_t)hl1 * 512 + of1);
    }

    // B fragments from LDS (swizzled ds_read_b128)
    const char* buf = bsm[ht & 1];
    short8 bf[8];
    #pragma unroll
    for (int s = 0; s < 8; ++s) {
      int off = (lg * 16 + s * 64) ^ ((ll & 7) << 4);
      bf[s] = *(const short8*)(buf + ll * 512 + off);
    }

    f32x4 a0 = {0.f, 0.f, 0.f, 0.f};
    f32x4 a1 = {0.f, 0.f, 0.f, 0.f};
    #pragma unroll
    for (int s = 0; s < 8; ++s) {
      a0 = __builtin_amdgcn_mfma_f32_16x16x32_bf16(af0[s], bf[s], a0, 0, 0, 0);
      a1 = __builtin_amdgcn_mfma_f32_16x16x32_bf16(af1[s], bf[s], a1, 0, 0, 0);
    }

    const int h = ht * 16 + ll;
    const float qb = qp[bn * HH + h] + wk_b[h];
    const float wv = wv_w[h];
    #pragma unroll
    for (int r = 0; r < 4; ++r) p0[r] += wv * tanhf_fast(a0[r] + qb);
    #pragma unroll
    for (int r = 0; r < 4; ++r) p1[r] += wv * tanhf_fast(a1[r] + qb);

    if (ht < 31) {
      char* nb = bsm[(ht + 1) & 1];
      *(int4*)(nb + d0) = n0;
      *(int4*)(nb + d1) = n1;
    }
    __syncthreads();
  }

  // --- reduce over h (16 lanes of each lane-group) ---
  #pragma unroll
  for (int r = 0; r < 4; ++r) {
    #pragma unroll
    for (int off = 1; off <= 8; off <<= 1) {
      p0[r] += __shfl_xor(p0[r], off, 64);
      p1[r] += __shfl_xor(p1[r], off, 64);
    }
  }
  if (ll == 0) {
    #pragma unroll
    for (int r = 0; r < 4; ++r) {
      sc[w * 32 + lg * 4 + r]      = p0[r];
      sc[w * 32 + 16 + lg * 4 + r] = p1[r];
    }
  }
  __syncthreads();

  // --- masked softmax over K=128 (wv_b omitted: softmax shift-invariant) ---
  if (t < KK) sc[t] += (float)masks[bn * KK + t] * (-1e9f);
  __syncthreads();
  if (t < 64) {
    float a = fmaxf(sc[t], sc[t + 64]);
    #pragma unroll
    for (int off = 32; off >= 1; off >>= 1) a = fmaxf(a, __shfl_xor(a, off, 64));
    if (t == 0) red[0] = a;
  }
  __syncthreads();
  const float m = red[0];
  if (t < KK) sc[t] = expf(sc[t] - m);
  __syncthreads();
  if (t < 64) {
    float a = sc[t] + sc[t + 64];
    #pragma unroll
    for (int off = 32; off >= 1; off >>= 1) a += __shfl_xor(a, off, 64);
    if (t == 0) red[1] = a;
  }
  __syncthreads();
  const float inv = 1.f / red[1];
  if (t < KK) {
    float wgt = sc[t] * inv;
    sc[t] = wgt;
    out[BN * EE + bn * KK + t] = wgt;      // attn_weight
  }
  __syncthreads();

  // --- attn_out[bn][e=t] = sum_k w[k] * keys[bn,k,e] (f32 keys) ---
  const float* kb = keys + (size_t)bn * KK * EE;
  float acc = 0.f;
  #pragma unroll 8
  for (int k = 0; k < KK; ++k)
    acc += sc[k] * kb[k * EE + t];
  out[bn * EE + t] = acc;
}

// ---------------------------------------------------------------------------
extern "C" void kernel_launch(void* const* d_in, const int* in_sizes, int n_in,
                              void* d_out, int out_size, void* d_ws, size_t ws_size,
                              hipStream_t stream) {
  const float* queries = (const float*)d_in[0];
  const float* keys    = (const float*)d_in[1];
  const int*   masks   = (const int*)d_in[2];
  // d_in[3] = num_neg (unused)
  const float* wk_w = (const float*)d_in[4];
  const float* wk_b = (const float*)d_in[5];
  const float* wq_w = (const float*)d_in[6];
  const float* wq_b = (const float*)d_in[7];
  const float* wv_w = (const float*)d_in[8];
  // d_in[9] = wv_b (softmax shift-invariant -> unused)

  float* out = (float*)d_out;
  float* qp  = (float*)d_ws;                              // 512*512 f32 = 1 MB
  unsigned short* wk_bf = (unsigned short*)(qp + BN * HH); // 512*256 bf16 = 256 KB

  k_wk_bf16<<<512, 256, 0, stream>>>(wk_w, wk_bf);
  k_qproj<<<BN, 256, 0, stream>>>(queries, wq_w, wq_b, qp);
  k_fused<<<BN, 256, 0, stream>>>(keys, wk_bf, wk_b, wv_w, qp, masks, out);
}

// Round 5
// 66.717 us; speedup vs baseline: 6.2600x; 1.2246x over previous
//
#include <hip/hip_runtime.h>
#include <hip/hip_bf16.h>

// Problem constants
#define B_  64
#define N1_ 8
#define KK  128
#define EE  256
#define HH  512
#define BN  (B_ * N1_)   // 512

typedef __attribute__((ext_vector_type(8))) short short8;   // bf16x8 MFMA frag
typedef __attribute__((ext_vector_type(4))) float f32x4;    // MFMA acc

__device__ __forceinline__ short bfs(float f) {
  __hip_bfloat16 h = __float2bfloat16(f);   // RNE, lowers to v_cvt_pk_bf16_f32
  return __builtin_bit_cast(short, h);
}

__device__ __forceinline__ float tanhf_fast(float x) {
  // tanh(x) = 1 - 2/(exp(2x)+1);  exp(2x) = exp2(2*log2e*x)
  float e2 = __builtin_amdgcn_exp2f(2.8853900817779268f * x);
  return 1.0f - 2.0f * __builtin_amdgcn_rcpf(e2 + 1.0f);
}

// ---------------------------------------------------------------------------
// k_prep: blocks 0..511   -> qp[bn][h] = dot(q,wq[h]) + wq_b[h] + wk_b[h]
//         blocks 512..639 -> wk_w f32 -> bf16
// qproj is wave-per-row: 64 lanes each load one float4 of the row (coalesced),
// 6-step butterfly reduce; 4 rows batched for latency.
// ---------------------------------------------------------------------------
__global__ __launch_bounds__(256) void k_prep(
    const float* __restrict__ queries,
    const float* __restrict__ wq_w,
    const float* __restrict__ wq_b,
    const float* __restrict__ wk_b,
    const float* __restrict__ wk_w,
    float* __restrict__ qp,
    unsigned short* __restrict__ wk_bf) {
  const int bid = blockIdx.x;
  const int t = threadIdx.x;
  if (bid < BN) {
    const int w = t >> 6, l = t & 63;
    const int bn = bid;
    float4 q4 = *(const float4*)(queries + (size_t)bn * EE + l * 4);
    const int h0 = w * 128;
    float keep[2] = {0.f, 0.f};
    #pragma unroll 2
    for (int g = 0; g < 2; ++g) {            // 2 groups of 64 rows
      float kp = 0.f;
      for (int i = 0; i < 64; i += 4) {      // 4 rows in flight
        const float* base = wq_w + (size_t)(h0 + g * 64 + i) * EE + l * 4;
        float4 w0 = *(const float4*)(base);
        float4 w1 = *(const float4*)(base + EE);
        float4 w2 = *(const float4*)(base + 2 * EE);
        float4 w3 = *(const float4*)(base + 3 * EE);
        float s0 = w0.x*q4.x + w0.y*q4.y + w0.z*q4.z + w0.w*q4.w;
        float s1 = w1.x*q4.x + w1.y*q4.y + w1.z*q4.z + w1.w*q4.w;
        float s2 = w2.x*q4.x + w2.y*q4.y + w2.z*q4.z + w2.w*q4.w;
        float s3 = w3.x*q4.x + w3.y*q4.y + w3.z*q4.z + w3.w*q4.w;
        #pragma unroll
        for (int off = 1; off <= 32; off <<= 1) {
          s0 += __shfl_xor(s0, off, 64);
          s1 += __shfl_xor(s1, off, 64);
          s2 += __shfl_xor(s2, off, 64);
          s3 += __shfl_xor(s3, off, 64);
        }
        if (l == i)     kp = s0;
        if (l == i + 1) kp = s1;
        if (l == i + 2) kp = s2;
        if (l == i + 3) kp = s3;
      }
      keep[g] = kp;
    }
    #pragma unroll 2
    for (int g = 0; g < 2; ++g) {
      int h = h0 + g * 64 + l;
      qp[(size_t)bn * HH + h] = keep[g] + wq_b[h] + wk_b[h];
    }
  } else {
    int i = ((bid - BN) * 256 + t) * 4;
    float4 v = *(const float4*)(wk_w + i);
    union { unsigned short u[4]; uint2 p; } pk;
    pk.u[0] = (unsigned short)bfs(v.x);
    pk.u[1] = (unsigned short)bfs(v.y);
    pk.u[2] = (unsigned short)bfs(v.z);
    pk.u[3] = (unsigned short)bfs(v.w);
    *(uint2*)(wk_bf + i) = pk.p;
  }
}

// ---------------------------------------------------------------------------
// k_fused: one block = one bn (128 key-rows), 8 waves x 16 rows.
// wk tiles (16h x 256e bf16 = 8 KB) double-buffered in LDS (XOR-swizzled),
// one barrier/tile. qb (= qproj + wq_b + wk_b) and wv staged in LDS once.
// scores -> masked softmax -> attn_weight + attn_out, all in-block.
// MFMA 16x16x32 C/D: col(h)=lane&15, row(key)=(lane>>4)*4+reg   [m89]
// ---------------------------------------------------------------------------
__global__ __launch_bounds__(512) void k_fused(
    const float* __restrict__ keys,
    const unsigned short* __restrict__ wk_bf,
    const float* __restrict__ wv_w,
    const float* __restrict__ qp,
    const int* __restrict__ masks,
    float* __restrict__ out) {
  const int t  = threadIdx.x;
  const int w  = t >> 6;      // wave 0..7
  const int l  = t & 63;
  const int lg = l >> 4;      // lane group 0..3
  const int ll = l & 15;
  const int bn = blockIdx.x;

  __shared__ __align__(16) char bsm[2][16 * 512];  // 2 x 8 KB wk tiles
  __shared__ float qb_s[HH];
  __shared__ float wv_s[HH];
  __shared__ float sc[KK];
  __shared__ float po[512];
  __shared__ float red[2];

  // stage per-block scalars (coalesced, once)
  qb_s[t] = qp[(size_t)bn * HH + t];
  wv_s[t] = wv_w[t];

  // wk-tile staging: 512 threads x one 16B chunk
  const char* wkb = (const char*)wk_bf;            // 512 rows x 512 B
  const int hl = t >> 5;                            // h-local 0..15
  const int of = (t & 31) * 16;
  const int dsw  = hl * 512 + (of ^ ((hl & 7) << 4));
  const int gsrc = hl * 512 + of;

  // prologue: stage tile 0
  int4 s0 = *(const int4*)(wkb + gsrc);
  *(int4*)(bsm[0] + dsw) = s0;

  // this wave's 16 rows x 256 e keys -> bf16 A-fragments (in regs)
  short8 af[8];
  {
    const float* kp = keys + (size_t)(bn * KK + w * 16 + ll) * EE + lg * 8;
    #pragma unroll
    for (int s = 0; s < 8; ++s) {
      float4 x = *(const float4*)(kp + s * 32);
      float4 y = *(const float4*)(kp + s * 32 + 4);
      short8 f;
      f[0] = bfs(x.x); f[1] = bfs(x.y); f[2] = bfs(x.z); f[3] = bfs(x.w);
      f[4] = bfs(y.x); f[5] = bfs(y.y); f[6] = bfs(y.z); f[7] = bfs(y.w);
      af[s] = f;
    }
  }
  __syncthreads();

  float part[4] = {0.f, 0.f, 0.f, 0.f};

  for (int ht = 0; ht < HH / 16; ++ht) {     // 32 wk tiles
    int4 nx;
    if (ht < 31) nx = *(const int4*)(wkb + (size_t)(ht + 1) * 8192 + gsrc);

    const char* buf = bsm[ht & 1];
    short8 bf[8];
    #pragma unroll
    for (int s = 0; s < 8; ++s) {
      int off = (lg * 16 + s * 64) ^ ((ll & 7) << 4);
      bf[s] = *(const short8*)(buf + ll * 512 + off);
    }
    const int h = ht * 16 + ll;
    const float qb = qb_s[h];     // LDS broadcast
    const float wv = wv_s[h];

    f32x4 a = {0.f, 0.f, 0.f, 0.f};
    #pragma unroll
    for (int s = 0; s < 8; ++s)
      a = __builtin_amdgcn_mfma_f32_16x16x32_bf16(af[s], bf[s], a, 0, 0, 0);

    #pragma unroll
    for (int r = 0; r < 4; ++r)
      part[r] += wv * tanhf_fast(a[r] + qb);

    if (ht < 31) *(int4*)(bsm[(ht + 1) & 1] + dsw) = nx;
    __syncthreads();
  }

  // reduce over h (16 lanes of each lane-group)
  #pragma unroll
  for (int r = 0; r < 4; ++r) {
    #pragma unroll
    for (int off = 1; off <= 8; off <<= 1)
      part[r] += __shfl_xor(part[r], off, 64);
  }
  if (ll == 0) {
    #pragma unroll
    for (int r = 0; r < 4; ++r)
      sc[w * 16 + lg * 4 + r] = part[r];
  }
  __syncthreads();

  // masked softmax over K=128 (wv_b omitted: softmax shift-invariant)
  if (t < KK) sc[t] += (float)masks[bn * KK + t] * (-1e9f);
  __syncthreads();
  if (t < 64) {
    float a = fmaxf(sc[t], sc[t + 64]);
    #pragma unroll
    for (int off = 32; off >= 1; off >>= 1) a = fmaxf(a, __shfl_xor(a, off, 64));
    if (t == 0) red[0] = a;
  }
  __syncthreads();
  const float m = red[0];
  if (t < KK) sc[t] = expf(sc[t] - m);
  __syncthreads();
  if (t < 64) {
    float a = sc[t] + sc[t + 64];
    #pragma unroll
    for (int off = 32; off >= 1; off >>= 1) a += __shfl_xor(a, off, 64);
    if (t == 0) red[1] = a;
  }
  __syncthreads();
  const float inv = 1.f / red[1];
  if (t < KK) {
    float wgt = sc[t] * inv;
    sc[t] = wgt;
    out[BN * EE + (size_t)bn * KK + t] = wgt;   // attn_weight
  }
  __syncthreads();

  // attn_out[bn][e] = sum_k w[k]*keys[bn,k,e]; split k across thread halves
  const int e = t & 255, kh = t >> 8;
  const float* kb = keys + (size_t)bn * KK * EE + (size_t)kh * 64 * EE;
  float acc = 0.f;
  #pragma unroll 8
  for (int k = 0; k < 64; ++k)
    acc += sc[kh * 64 + k] * kb[k * EE + e];    // coalesced over e
  po[t] = acc;
  __syncthreads();
  if (t < 256) out[(size_t)bn * EE + t] = po[t] + po[t + 256];
}

// ---------------------------------------------------------------------------
extern "C" void kernel_launch(void* const* d_in, const int* in_sizes, int n_in,
                              void* d_out, int out_size, void* d_ws, size_t ws_size,
                              hipStream_t stream) {
  const float* queries = (const float*)d_in[0];
  const float* keys    = (const float*)d_in[1];
  const int*   masks   = (const int*)d_in[2];
  // d_in[3] = num_neg (unused)
  const float* wk_w = (const float*)d_in[4];
  const float* wk_b = (const float*)d_in[5];
  const float* wq_w = (const float*)d_in[6];
  const float* wq_b = (const float*)d_in[7];
  const float* wv_w = (const float*)d_in[8];
  // d_in[9] = wv_b (softmax shift-invariant -> unused)

  float* out = (float*)d_out;
  float* qp  = (float*)d_ws;                               // 512*512 f32 = 1 MB
  unsigned short* wk_bf = (unsigned short*)(qp + BN * HH); // 512*256 bf16 = 256 KB

  k_prep<<<BN + 128, 256, 0, stream>>>(queries, wq_w, wq_b, wk_b, wk_w, qp, wk_bf);
  k_fused<<<BN, 512, 0, stream>>>(keys, wk_bf, wv_w, qp, masks, out);
}